// Round 8
// baseline (897.776 us; speedup 1.0000x reference)
//
#include <hip/hip_runtime.h>
#include <hip/hip_cooperative_groups.h>

namespace cg = cooperative_groups;

#define F 128
#define SCANB 1024
#define NBLK 128      // hist/scatter parallel width == mat columns
#define MAXNB 3328    // max buckets (fits lh in the 43 KB smem union)
#define CBLKS 768     // cooperative grid: 3 blocks/CU x 256 CU
#define SMEM_BYTES 43264

typedef __attribute__((ext_vector_type(8))) short short8;
typedef __attribute__((ext_vector_type(4))) float f32x4;

static __device__ __forceinline__ short f2bf(float f) {
    union { float f; unsigned u; } v; v.f = f;
    unsigned r = v.u + 0x7FFF + ((v.u >> 16) & 1);   // round-to-nearest-even
    return (short)(r >> 16);
}
static __device__ __forceinline__ float bf_lo(unsigned u) {
    return __builtin_bit_cast(float, u << 16);
}
static __device__ __forceinline__ float bf_hi(unsigned u) {
    return __builtin_bit_cast(float, u & 0xFFFF0000u);
}
static __device__ __forceinline__ uint4 pack8(float a0,float a1,float a2,float a3,
                                              float a4,float a5,float a6,float a7) {
    uint4 o;
    o.x = ((unsigned)(unsigned short)f2bf(a1) << 16) | (unsigned short)f2bf(a0);
    o.y = ((unsigned)(unsigned short)f2bf(a3) << 16) | (unsigned short)f2bf(a2);
    o.z = ((unsigned)(unsigned short)f2bf(a5) << 16) | (unsigned short)f2bf(a4);
    o.w = ((unsigned)(unsigned short)f2bf(a7) << 16) | (unsigned short)f2bf(a6);
    return o;
}

// ================= cooperative mega-kernel: GEMM || CSR build ==============
// P1: blocks<NBLK build per-(bucket,block) hist; blocks>=NBLK do hW GEMM.
// P2: grid-synced hierarchical exclusive scan of mat (bucket-major).
// P3: blocks<NBLK scatter packed (ldst,src) into bucket-major binned[].
// P4: all blocks finalize CSR per bucket (deg/offs/esrc), LDS-local.
__global__ __launch_bounds__(256) void k_coop(
    const float* __restrict__ h, const float* __restrict__ w,
    const int* __restrict__ src, const int* __restrict__ dst,
    unsigned* __restrict__ hb, int* __restrict__ mat, int* __restrict__ bsum,
    unsigned* __restrict__ binned, int* __restrict__ deg,
    int* __restrict__ offs, int* __restrict__ esrc,
    int n_nodes, int n_edges, int nb, int bshift)
{
    cg::grid_group grid = cg::this_grid();
    __shared__ alignas(16) char smem[SMEM_BYTES];
    short* wt = (short*)smem;               // [128*136] bf16 W^T   (34816 B)
    float* xs = (float*)(smem + 34816);     // [4][4][132] C bounce (8448 B)
    int*   lh = (int*)smem;                 // overlay: hist/scan/csr scratch

    const int tid = threadIdx.x;
    const int bid = blockIdx.x;

    // ---------------- P1: hist || GEMM ----------------
    if (bid < NBLK) {
        for (int i = tid; i < nb; i += 256) lh[i] = 0;
        __syncthreads();
        const int epb = (n_edges + NBLK - 1) / NBLK;
        const int e0 = bid * epb, e1 = min(e0 + epb, n_edges);
        for (int e = e0 + tid; e < e1; e += 256)
            atomicAdd(&lh[dst[e] >> bshift], 1);
        __syncthreads();
        for (int i = tid; i < nb; i += 256)
            mat[(size_t)i * NBLK + bid] = lh[i];
    } else {
        { int n = tid & 127;
          for (int k = tid >> 7; k < 128; k += 2)
              wt[n * 136 + k] = f2bf(w[(size_t)k * 128 + n]); }
        __syncthreads();
        const int wv = tid >> 6, l = tid & 63, lr = l & 15, lk = l >> 4, q = l & 15;
        float* xw = xs + wv * (4 * 132);
        for (int base = (bid - NBLK) * 64; base < n_nodes;
             base += (CBLKS - NBLK) * 64) {
            const int row = base + wv * 16 + lr;
            const bool valid = row < n_nodes;
            short8 af[4];
            #pragma unroll
            for (int kk = 0; kk < 4; ++kk) {
                int k0 = kk * 32 + lk * 8;
                float4 a0{0,0,0,0}, a1{0,0,0,0};
                if (valid) {
                    a0 = *(const float4*)(h + (size_t)row * F + k0);
                    a1 = *(const float4*)(h + (size_t)row * F + k0 + 4);
                }
                af[kk] = short8{ f2bf(a0.x), f2bf(a0.y), f2bf(a0.z), f2bf(a0.w),
                                 f2bf(a1.x), f2bf(a1.y), f2bf(a1.z), f2bf(a1.w) };
            }
            f32x4 acc[8];
            #pragma unroll
            for (int n = 0; n < 8; ++n) acc[n] = f32x4{0, 0, 0, 0};
            #pragma unroll
            for (int kk = 0; kk < 4; ++kk) {
                const int kb = kk * 32 + lk * 8;
                #pragma unroll
                for (int n = 0; n < 8; ++n) {
                    short8 bfr = *(const short8*)(&wt[(n * 16 + lr) * 136 + kb]);
                    acc[n] = __builtin_amdgcn_mfma_f32_16x16x32_bf16(af[kk], bfr, acc[n], 0, 0, 0);
                }
            }
            // bounce one r-group (4 rows) at a time through per-wave LDS
            #pragma unroll
            for (int r = 0; r < 4; ++r) {
                #pragma unroll
                for (int n = 0; n < 8; ++n)
                    xw[lk * 132 + n * 16 + lr] = acc[n][r];
                int grow = base + wv * 16 + lk * 4 + r;
                float4 a = *(const float4*)&xw[lk * 132 + q * 8];
                float4 b = *(const float4*)&xw[lk * 132 + q * 8 + 4];
                uint4 o = pack8(a.x, a.y, a.z, a.w, b.x, b.y, b.z, b.w);
                if (grow < n_nodes)
                    ((uint4*)hb)[(size_t)grow * 16 + q] = o;
            }
        }
    }
    __threadfence();
    grid.sync();

    // ---------------- P2a: per-block chunk exclusive scan ----------------
    const int len = nb * NBLK;
    const int chunk = (len + CBLKS - 1) / CBLKS;
    const int c0 = bid * chunk;
    const int c1 = min(c0 + chunk, len);
    const int cn = max(c1 - c0, 0);
    for (int i = tid; i < cn; i += 256) lh[i] = mat[c0 + i];
    __syncthreads();
    if (tid == 0) {
        int run = 0;
        for (int i = 0; i < cn; ++i) { int t = lh[i]; lh[i] = run; run += t; }
        bsum[bid] = run;
    }
    __syncthreads();
    __threadfence();
    grid.sync();

    // ---------------- P2b: scan of block totals ----------------
    if (bid == 0 && tid == 0) {
        int run = 0;
        for (int b = 0; b < CBLKS; ++b) { int t = bsum[b]; bsum[b] = run; run += t; }
    }
    __threadfence();
    grid.sync();

    // ---------------- P2c: add base, write back ----------------
    {
        const int basev = bsum[bid];
        for (int i = tid; i < cn; i += 256) mat[c0 + i] = lh[i] + basev;
    }
    __threadfence();
    grid.sync();

    // ---------------- P3: binned scatter (blocks < NBLK) ----------------
    if (bid < NBLK) {
        __syncthreads();
        for (int i = tid; i < nb; i += 256)
            lh[i] = mat[(size_t)i * NBLK + bid];
        __syncthreads();
        const int epb = (n_edges + NBLK - 1) / NBLK;
        const int e0 = bid * epb, e1 = min(e0 + epb, n_edges);
        for (int e = e0 + tid; e < e1; e += 256) {
            int d = dst[e];
            int b = d >> bshift;
            int pos = atomicAdd(&lh[b], 1);   // LDS atomic only
            binned[pos] = ((unsigned)(d & ((1 << bshift) - 1)) << 26) | (unsigned)src[e];
        }
    }
    __threadfence();
    grid.sync();

    // ---------------- P4: bucket -> CSR ----------------
    int* ldeg  = lh;
    int* loffs = lh + 64;
    int* lcur  = lh + 128;
    for (int b = bid; b < nb; b += CBLKS) {
        __syncthreads();
        int start = mat[(size_t)b * NBLK];
        int end   = (b + 1 < nb) ? mat[(size_t)(b + 1) * NBLK] : n_edges;
        int cnt = end - start;
        int base_node = b << bshift;
        int nn = min(1 << bshift, n_nodes - base_node);
        for (int i = tid; i < nn; i += 256) { ldeg[i] = 0; lcur[i] = 0; }
        __syncthreads();
        for (int i = tid; i < cnt; i += 256)
            atomicAdd(&ldeg[binned[start + i] >> 26], 1);
        __syncthreads();
        if (tid == 0) {
            int run = 0;
            for (int i = 0; i < nn; ++i) { loffs[i] = run; run += ldeg[i]; }
        }
        __syncthreads();
        for (int i = tid; i < nn; i += 256) {
            deg[base_node + i]  = ldeg[i];
            offs[base_node + i] = start + loffs[i];
        }
        for (int i = tid; i < cnt; i += 256) {
            unsigned p = binned[start + i];
            int ln = p >> 26;
            int pos = start + loffs[ln] + atomicAdd(&lcur[ln], 1);
            esrc[pos] = (int)(p & ((1u << 26) - 1));
        }
    }
}

// ================= fallback kernels (round-7 chain) ========================
__global__ __launch_bounds__(256) void k_part_hist(
    const int* __restrict__ dst, int* __restrict__ mat,
    int n_edges, int nb, int bshift, int epb) {
    __shared__ int lh[MAXNB];
    for (int i = threadIdx.x; i < nb; i += 256) lh[i] = 0;
    __syncthreads();
    int e0 = blockIdx.x * epb;
    int e1 = min(e0 + epb, n_edges);
    for (int e = e0 + threadIdx.x; e < e1; e += 256)
        atomicAdd(&lh[dst[e] >> bshift], 1);
    __syncthreads();
    for (int i = threadIdx.x; i < nb; i += 256)
        mat[(size_t)i * NBLK + blockIdx.x] = lh[i];
}

__global__ __launch_bounds__(SCANB) void k_scan_a(const int* in, int* out,
                                                  int* bsum, int n) {
    __shared__ int tmp[SCANB];
    int i = blockIdx.x * SCANB + threadIdx.x;
    int v = (i < n) ? in[i] : 0;
    tmp[threadIdx.x] = v;
    __syncthreads();
    for (int off = 1; off < SCANB; off <<= 1) {
        int t = (threadIdx.x >= off) ? tmp[threadIdx.x - off] : 0;
        __syncthreads();
        tmp[threadIdx.x] += t;
        __syncthreads();
    }
    if (i < n) out[i] = tmp[threadIdx.x] - v;
    if (threadIdx.x == SCANB - 1) bsum[blockIdx.x] = tmp[SCANB - 1];
}

__global__ __launch_bounds__(512) void k_scan_b(int* bsum, int nb) {
    __shared__ int tmp[512];
    int i = threadIdx.x;
    int v = (i < nb) ? bsum[i] : 0;
    tmp[i] = v;
    __syncthreads();
    for (int off = 1; off < 512; off <<= 1) {
        int t = (i >= off) ? tmp[i - off] : 0;
        __syncthreads();
        tmp[i] += t;
        __syncthreads();
    }
    if (i < nb) bsum[i] = tmp[i] - v;
}

__global__ __launch_bounds__(SCANB) void k_scan_c(int* out, const int* bsum, int n) {
    int i = blockIdx.x * SCANB + threadIdx.x;
    if (i < n) out[i] += bsum[blockIdx.x];
}

__global__ __launch_bounds__(256) void k_part_scatter(
    const int* __restrict__ src, const int* __restrict__ dst,
    const int* __restrict__ mat, unsigned* __restrict__ binned,
    int n_edges, int nb, int bshift, int epb) {
    __shared__ int lbase[MAXNB];
    int e0 = blockIdx.x * epb;
    int e1 = min(e0 + epb, n_edges);
    for (int i = threadIdx.x; i < nb; i += 256)
        lbase[i] = mat[(size_t)i * NBLK + blockIdx.x];
    __syncthreads();
    for (int e = e0 + threadIdx.x; e < e1; e += 256) {
        int d = dst[e];
        int b = d >> bshift;
        int pos = atomicAdd(&lbase[b], 1);
        binned[pos] = ((unsigned)(d & ((1 << bshift) - 1)) << 26) | (unsigned)src[e];
    }
}

__global__ __launch_bounds__(256) void k_bin_to_csr(
    const unsigned* __restrict__ binned, const int* __restrict__ mat,
    int* __restrict__ deg, int* __restrict__ offs, int* __restrict__ esrc,
    int n_edges, int n_nodes, int nb, int bshift) {
    __shared__ int ldeg[64], loffs[64], lcur[64];
    int b = blockIdx.x;
    int start = mat[(size_t)b * NBLK];
    int end   = (b + 1 < nb) ? mat[(size_t)(b + 1) * NBLK] : n_edges;
    int cnt = end - start;
    int base_node = b << bshift;
    int nn = min(1 << bshift, n_nodes - base_node);
    for (int i = threadIdx.x; i < nn; i += 256) { ldeg[i] = 0; lcur[i] = 0; }
    __syncthreads();
    for (int i = threadIdx.x; i < cnt; i += 256)
        atomicAdd(&ldeg[binned[start + i] >> 26], 1);
    __syncthreads();
    if (threadIdx.x == 0) {
        int run = 0;
        for (int i = 0; i < nn; ++i) { loffs[i] = run; run += ldeg[i]; }
    }
    __syncthreads();
    for (int i = threadIdx.x; i < nn; i += 256) {
        deg[base_node + i]  = ldeg[i];
        offs[base_node + i] = start + loffs[i];
    }
    for (int i = threadIdx.x; i < cnt; i += 256) {
        unsigned p = binned[start + i];
        int ln = p >> 26;
        int pos = start + loffs[ln] + atomicAdd(&lcur[ln], 1);
        esrc[pos] = (int)(p & ((1u << 26) - 1));
    }
}

__global__ __launch_bounds__(256) void k_hist(const int* __restrict__ dst,
                                              int* __restrict__ deg, int n_edges) {
    int e = blockIdx.x * 256 + threadIdx.x;
    if (e < n_edges) atomicAdd(&deg[dst[e]], 1);
}

__global__ __launch_bounds__(256) void k_scatter_idx(
    const int* __restrict__ src, const int* __restrict__ dst,
    const int* __restrict__ offs, int* __restrict__ cursor,
    int* __restrict__ esrc, int n_edges) {
    int e = blockIdx.x * 256 + threadIdx.x;
    if (e >= n_edges) return;
    int d = dst[e];
    int pos = offs[d] + atomicAdd(&cursor[d], 1);
    esrc[pos] = src[e];
}

// standalone GEMM (fallback path): hb = bf16(h @ W)
__global__ __launch_bounds__(256) void k_gemm_hw(
    const float* __restrict__ h, const float* __restrict__ w,
    unsigned* __restrict__ hb, int n_nodes) {
    __shared__ short wt[128 * 136];
    __shared__ float xs[4][16][132];

    const int tid = threadIdx.x;
    {
        int n = tid & 127;
        for (int k = tid >> 7; k < 128; k += 2)
            wt[n * 136 + k] = f2bf(w[(size_t)k * 128 + n]);
    }
    __syncthreads();

    const int wv = tid >> 6, l = tid & 63, lr = l & 15, lk = l >> 4, q = l & 15;

    for (int base = blockIdx.x * 64; base < n_nodes; base += gridDim.x * 64) {
        const int row = base + wv * 16 + lr;
        const bool valid = row < n_nodes;
        short8 af[4];
        #pragma unroll
        for (int kk = 0; kk < 4; ++kk) {
            int k0 = kk * 32 + lk * 8;
            float4 a0{0,0,0,0}, a1{0,0,0,0};
            if (valid) {
                a0 = *(const float4*)(h + (size_t)row * F + k0);
                a1 = *(const float4*)(h + (size_t)row * F + k0 + 4);
            }
            af[kk] = short8{ f2bf(a0.x), f2bf(a0.y), f2bf(a0.z), f2bf(a0.w),
                             f2bf(a1.x), f2bf(a1.y), f2bf(a1.z), f2bf(a1.w) };
        }
        f32x4 acc[8];
        #pragma unroll
        for (int n = 0; n < 8; ++n) acc[n] = f32x4{0, 0, 0, 0};
        #pragma unroll
        for (int kk = 0; kk < 4; ++kk) {
            const int kb = kk * 32 + lk * 8;
            #pragma unroll
            for (int n = 0; n < 8; ++n) {
                short8 bfr = *(const short8*)(&wt[(n * 16 + lr) * 136 + kb]);
                acc[n] = __builtin_amdgcn_mfma_f32_16x16x32_bf16(af[kk], bfr, acc[n], 0, 0, 0);
            }
        }
        #pragma unroll
        for (int n = 0; n < 8; ++n)
            #pragma unroll
            for (int r = 0; r < 4; ++r)
                xs[wv][lk * 4 + r][n * 16 + lr] = acc[n][r];
        #pragma unroll
        for (int rr = 0; rr < 4; ++rr) {
            int lrow = rr * 4 + lk;
            int grow = base + wv * 16 + lrow;
            float4 a = *(const float4*)&xs[wv][lrow][q * 8];
            float4 b = *(const float4*)&xs[wv][lrow][q * 8 + 4];
            uint4 o = pack8(a.x, a.y, a.z, a.w, b.x, b.y, b.z, b.w);
            if (grow < n_nodes)
                ((uint4*)hb)[(size_t)grow * 16 + q] = o;
        }
    }
}

// ========== gather hW rows + norm + bias + LayerNorm + ReLU ================
__global__ __launch_bounds__(256) void k_gather_ln(
    const unsigned* __restrict__ hb, const int* __restrict__ esrc,
    const int* __restrict__ offs, const int* __restrict__ deg,
    const float* __restrict__ bias, const float* __restrict__ gamma,
    const float* __restrict__ beta, float* __restrict__ out, int n_nodes) {
    int t = blockIdx.x * 256 + threadIdx.x;
    int node = t >> 6;
    int lane = t & 63;
    if (node >= n_nodes) return;
    int start = offs[node];
    int dn = deg[node];
    float ax = 0.0f, ay = 0.0f;
    int i = 0;
    for (; i + 8 <= dn; i += 8) {
        #pragma unroll
        for (int u = 0; u < 8; ++u) {
            int s = esrc[start + i + u];
            unsigned v = hb[(size_t)s * 64 + lane];
            ax += bf_lo(v); ay += bf_hi(v);
        }
    }
    for (; i < dn; ++i) {
        int s = esrc[start + i];
        unsigned v = hb[(size_t)s * 64 + lane];
        ax += bf_lo(v); ay += bf_hi(v);
    }
    float nv = dn > 0 ? 1.0f / (float)dn : 0.0f;
    float fx = ax * nv + bias[2 * lane];
    float fy = ay * nv + bias[2 * lane + 1];

    float s = fx + fy, q = fx * fx + fy * fy;
    #pragma unroll
    for (int m = 1; m < 64; m <<= 1) {
        s += __shfl_xor(s, m);
        q += __shfl_xor(q, m);
    }
    float mu   = s * (1.0f / F);
    float var  = q * (1.0f / F) - mu * mu;
    float rstd = rsqrtf(var + 1e-5f);

    float y0 = fmaxf((fx - mu) * rstd * gamma[2 * lane]     + beta[2 * lane],     0.0f);
    float y1 = fmaxf((fy - mu) * rstd * gamma[2 * lane + 1] + beta[2 * lane + 1], 0.0f);
    ((float2*)out)[(size_t)node * 64 + lane] = make_float2(y0, y1);
}

extern "C" void kernel_launch(void* const* d_in, const int* in_sizes, int n_in,
                              void* d_out, int out_size, void* d_ws, size_t ws_size,
                              hipStream_t stream) {
    const float* h      = (const float*)d_in[0];
    const float* weight = (const float*)d_in[1];
    const float* bias   = (const float*)d_in[2];
    const float* gamma  = (const float*)d_in[3];
    const float* beta   = (const float*)d_in[4];
    const int*   src    = (const int*)d_in[5];
    const int*   dst    = (const int*)d_in[6];

    int n_nodes = in_sizes[0] / F;
    int n_edges = in_sizes[5];

    float* x = (float*)d_out;

    int bshift = 5;
    while (bshift <= 6 && ((n_nodes + (1 << bshift) - 1) >> bshift) > MAXNB) ++bshift;
    int nb = (n_nodes + (1 << bshift) - 1) >> bshift;
    const bool shift_ok = (nb <= MAXNB) && (n_nodes <= (1 << 26));

    // ws ints: deg[N] | offs[N] | esrc[E] | hb[N*64 u32] | bsum[1024] |
    //          mat[nb*NBLK] | binned[E u32]     (fallback: cursor = mat slot)
    int* deg    = (int*)d_ws;
    int* offs   = deg + n_nodes;
    int* esrc   = offs + n_nodes;
    unsigned* hb = (unsigned*)(esrc + n_edges);
    int* bsum   = (int*)(hb + (size_t)n_nodes * 64);
    int* mat    = bsum + 1024;
    unsigned* binned = (unsigned*)(mat + (size_t)nb * NBLK);
    int* cursor = mat;

    size_t need_common = ((size_t)2 * n_nodes + (size_t)n_edges + 1024) * sizeof(int)
                       + (size_t)n_nodes * 64 * sizeof(unsigned);
    size_t need_new  = need_common + ((size_t)nb * NBLK + (size_t)n_edges) * sizeof(int);
    size_t need_fall = need_common + (size_t)n_nodes * sizeof(int);
    bool use_new = shift_ok && ws_size >= need_new;

    bool coop_done = false;
    if (use_new) {
        const int len = nb * NBLK;
        const int chunk = (len + CBLKS - 1) / CBLKS;
        if (chunk <= MAXNB) {
            void* kargs[] = {
                (void*)&h, (void*)&weight, (void*)&src, (void*)&dst,
                (void*)&hb, (void*)&mat, (void*)&bsum, (void*)&binned,
                (void*)&deg, (void*)&offs, (void*)&esrc,
                (void*)&n_nodes, (void*)&n_edges, (void*)&nb, (void*)&bshift };
            hipError_t st = hipLaunchCooperativeKernel(
                (void*)k_coop, dim3(CBLKS), dim3(256), kargs, 0, stream);
            if (st == hipSuccess) coop_done = true;
            else (void)hipGetLastError();
        }
    }

    if (!coop_done) {
        // round-7 multi-kernel chain
        int gb = (n_nodes + 63) / 64;
        k_gemm_hw<<<gb, 256, 0, stream>>>(h, weight, hb, n_nodes);

        if (use_new) {
            const int epb = (n_edges + NBLK - 1) / NBLK;
            const int len = nb * NBLK;
            const int nscan = (len + SCANB - 1) / SCANB;
            k_part_hist<<<NBLK, 256, 0, stream>>>(dst, mat, n_edges, nb, bshift, epb);
            k_scan_a<<<nscan, SCANB, 0, stream>>>(mat, mat, bsum, len);
            k_scan_b<<<1, 512, 0, stream>>>(bsum, nscan);
            k_scan_c<<<nscan, SCANB, 0, stream>>>(mat, bsum, len);
            k_part_scatter<<<NBLK, 256, 0, stream>>>(src, dst, mat, binned,
                                                     n_edges, nb, bshift, epb);
            k_bin_to_csr<<<nb, 256, 0, stream>>>(binned, mat, deg, offs, esrc,
                                                 n_edges, n_nodes, nb, bshift);
        } else if (ws_size >= need_fall) {
            const int nscan = (n_nodes + SCANB - 1) / SCANB;
            hipMemsetAsync(deg, 0, (size_t)n_nodes * sizeof(int), stream);
            hipMemsetAsync(cursor, 0, (size_t)n_nodes * sizeof(int), stream);
            k_hist<<<(n_edges + 255) / 256, 256, 0, stream>>>(dst, deg, n_edges);
            k_scan_a<<<nscan, SCANB, 0, stream>>>(deg, offs, bsum, n_nodes);
            k_scan_b<<<1, 512, 0, stream>>>(bsum, nscan);
            k_scan_c<<<nscan, SCANB, 0, stream>>>(offs, bsum, n_nodes);
            k_scatter_idx<<<(n_edges + 255) / 256, 256, 0, stream>>>(
                src, dst, offs, cursor, esrc, n_edges);
        }
    }

    int gblocks = (int)(((size_t)n_nodes * 64 + 255) / 256);
    k_gather_ln<<<gblocks, 256, 0, stream>>>(hb, esrc, offs, deg,
                                             bias, gamma, beta, x, n_nodes);
}

// Round 10
// 158.799 us; speedup vs baseline: 5.6535x; 5.6535x over previous
//
#include <hip/hip_runtime.h>

#define F 128
#define SCANB 1024
#define NBLK 128        // hist/scatter width == mat columns
#define BSHIFT 6        // 64 nodes per bucket
#define MAXNB 4096      // nb guard (scan_b / lbase capacity)
#define SMEM_BYTES 43264  // wt(34816) + xs[4][4][132](8448)

typedef __attribute__((ext_vector_type(8))) short short8;
typedef __attribute__((ext_vector_type(4))) float f32x4;

static __device__ __forceinline__ short f2bf(float f) {
    union { float f; unsigned u; } v; v.f = f;
    unsigned r = v.u + 0x7FFF + ((v.u >> 16) & 1);   // round-to-nearest-even
    return (short)(r >> 16);
}
static __device__ __forceinline__ float bf_lo(unsigned u) {
    return __builtin_bit_cast(float, u << 16);
}
static __device__ __forceinline__ float bf_hi(unsigned u) {
    return __builtin_bit_cast(float, u & 0xFFFF0000u);
}
static __device__ __forceinline__ uint4 pack8(float a0,float a1,float a2,float a3,
                                              float a4,float a5,float a6,float a7) {
    uint4 o;
    o.x = ((unsigned)(unsigned short)f2bf(a1) << 16) | (unsigned short)f2bf(a0);
    o.y = ((unsigned)(unsigned short)f2bf(a3) << 16) | (unsigned short)f2bf(a2);
    o.z = ((unsigned)(unsigned short)f2bf(a5) << 16) | (unsigned short)f2bf(a4);
    o.w = ((unsigned)(unsigned short)f2bf(a7) << 16) | (unsigned short)f2bf(a6);
    return o;
}

// ========== role-split kernel: blocks<hblk do dst-hist, rest do hW GEMM ====
// No grid sync: hist->mat and GEMM->hb are independent; the kernel boundary
// is the barrier for downstream consumers.
__global__ __launch_bounds__(256) void k_gemm_hist(
    const float* __restrict__ h, const float* __restrict__ w,
    unsigned* __restrict__ hb, const int* __restrict__ dst,
    int* __restrict__ mat, int n_nodes, int n_edges, int nb, int hblk) {
    __shared__ alignas(16) char smem[SMEM_BYTES];
    const int tid = threadIdx.x;
    const int bid = blockIdx.x;

    if (bid < hblk) {
        // ---- histogram role ----
        int* lh = (int*)smem;
        for (int i = tid; i < nb; i += 256) lh[i] = 0;
        __syncthreads();
        const int epb = (n_edges + hblk - 1) / hblk;
        const int e0 = bid * epb, e1 = min(e0 + epb, n_edges);
        for (int e = e0 + tid; e < e1; e += 256)
            atomicAdd(&lh[dst[e] >> BSHIFT], 1);
        __syncthreads();
        for (int i = tid; i < nb; i += 256)
            mat[(size_t)i * NBLK + bid] = lh[i];
        return;
    }

    // ---- GEMM role: rows [base, base+64) ----
    short* wt = (short*)smem;               // [128*136] bf16 W^T  (34816 B)
    float* xs = (float*)(smem + 34816);     // [4][4][132] per-wave C bounce
    {
        int n = tid & 127;
        for (int k = tid >> 7; k < 128; k += 2)
            wt[n * 136 + k] = f2bf(w[(size_t)k * 128 + n]);
    }
    __syncthreads();

    const int wv = tid >> 6, l = tid & 63, lr = l & 15, lk = l >> 4, q = l & 15;
    const int base = (bid - hblk) * 64;
    if (base >= n_nodes) return;
    const int row = base + wv * 16 + lr;
    const bool valid = row < n_nodes;

    short8 af[4];
    #pragma unroll
    for (int kk = 0; kk < 4; ++kk) {
        int k0 = kk * 32 + lk * 8;
        float4 a0{0,0,0,0}, a1{0,0,0,0};
        if (valid) {
            a0 = *(const float4*)(h + (size_t)row * F + k0);
            a1 = *(const float4*)(h + (size_t)row * F + k0 + 4);
        }
        af[kk] = short8{ f2bf(a0.x), f2bf(a0.y), f2bf(a0.z), f2bf(a0.w),
                         f2bf(a1.x), f2bf(a1.y), f2bf(a1.z), f2bf(a1.w) };
    }
    f32x4 acc[8];
    #pragma unroll
    for (int n = 0; n < 8; ++n) acc[n] = f32x4{0, 0, 0, 0};
    #pragma unroll
    for (int kk = 0; kk < 4; ++kk) {
        const int kb = kk * 32 + lk * 8;
        #pragma unroll
        for (int n = 0; n < 8; ++n) {
            short8 bfr = *(const short8*)(&wt[(n * 16 + lr) * 136 + kb]);
            acc[n] = __builtin_amdgcn_mfma_f32_16x16x32_bf16(af[kk], bfr, acc[n], 0, 0, 0);
        }
    }
    // per-r bounce (round-8-verified): row lk*4+r lives in LDS slot lk
    float* xw = xs + wv * (4 * 132);
    #pragma unroll
    for (int r = 0; r < 4; ++r) {
        #pragma unroll
        for (int n = 0; n < 8; ++n)
            xw[lk * 132 + n * 16 + lr] = acc[n][r];
        int grow = base + wv * 16 + lk * 4 + r;
        float4 a = *(const float4*)&xw[lk * 132 + q * 8];
        float4 b = *(const float4*)&xw[lk * 132 + q * 8 + 4];
        uint4 o = pack8(a.x, a.y, a.z, a.w, b.x, b.y, b.z, b.w);
        if (grow < n_nodes)
            ((uint4*)hb)[(size_t)grow * 16 + q] = o;
    }
}

// ========== exclusive scan (chunked; bsum holds per-chunk totals) ==========
__global__ __launch_bounds__(SCANB) void k_scan_a(const int* in, int* out,
                                                  int* bsum, int n) {
    __shared__ int tmp[SCANB];
    int i = blockIdx.x * SCANB + threadIdx.x;
    int v = (i < n) ? in[i] : 0;
    tmp[threadIdx.x] = v;
    __syncthreads();
    for (int off = 1; off < SCANB; off <<= 1) {
        int t = (threadIdx.x >= off) ? tmp[threadIdx.x - off] : 0;
        __syncthreads();
        tmp[threadIdx.x] += t;
        __syncthreads();
    }
    if (i < n) out[i] = tmp[threadIdx.x] - v;
    if (threadIdx.x == SCANB - 1) bsum[blockIdx.x] = tmp[SCANB - 1];
}

__global__ __launch_bounds__(512) void k_scan_b(int* bsum, int nb) {
    __shared__ int tmp[512];
    int i = threadIdx.x;
    int v = (i < nb) ? bsum[i] : 0;
    tmp[i] = v;
    __syncthreads();
    for (int off = 1; off < 512; off <<= 1) {
        int t = (i >= off) ? tmp[i - off] : 0;
        __syncthreads();
        tmp[i] += t;
        __syncthreads();
    }
    if (i < nb) bsum[i] = tmp[i] - v;
}

__global__ __launch_bounds__(SCANB) void k_scan_c(int* out, const int* bsum, int n) {
    int i = blockIdx.x * SCANB + threadIdx.x;
    if (i < n) out[i] += bsum[blockIdx.x];
}

// ========== binned scatter; scan_c folded in via bsum lookup ===============
__global__ __launch_bounds__(256) void k_part_scatter(
    const int* __restrict__ src, const int* __restrict__ dst,
    const int* __restrict__ mat, const int* __restrict__ bsum,
    unsigned* __restrict__ binned, int n_edges, int nb, int epb) {
    __shared__ int lbase[MAXNB];
    const int bid = blockIdx.x;
    for (int i = threadIdx.x; i < nb; i += 256) {
        int idx = i * NBLK + bid;
        lbase[i] = mat[idx] + bsum[idx >> 10];
    }
    __syncthreads();
    int e0 = bid * epb;
    int e1 = min(e0 + epb, n_edges);
    for (int e = e0 + threadIdx.x; e < e1; e += 256) {
        int d = dst[e];
        int b = d >> BSHIFT;
        int pos = atomicAdd(&lbase[b], 1);   // LDS atomic only
        binned[pos] = ((unsigned)(d & ((1 << BSHIFT) - 1)) << 26) | (unsigned)src[e];
    }
}

// ========== per-bucket CSR finalize; scan_c folded in ======================
__global__ __launch_bounds__(256) void k_bin_to_csr(
    const unsigned* __restrict__ binned, const int* __restrict__ mat,
    const int* __restrict__ bsum, int* __restrict__ deg, int* __restrict__ offs,
    int* __restrict__ esrc, int n_edges, int n_nodes, int nb) {
    __shared__ int ldeg[64], loffs[64], lcur[64];
    int b = blockIdx.x;
    int i0 = b * NBLK;
    int start = mat[i0] + bsum[i0 >> 10];
    int end = n_edges;
    if (b + 1 < nb) {
        int i1 = (b + 1) * NBLK;
        end = mat[i1] + bsum[i1 >> 10];
    }
    int cnt = end - start;
    int base_node = b << BSHIFT;
    int nn = min(1 << BSHIFT, n_nodes - base_node);
    for (int i = threadIdx.x; i < nn; i += 256) { ldeg[i] = 0; lcur[i] = 0; }
    __syncthreads();
    for (int i = threadIdx.x; i < cnt; i += 256)
        atomicAdd(&ldeg[binned[start + i] >> 26], 1);
    __syncthreads();
    if (threadIdx.x == 0) {
        int run = 0;
        for (int i = 0; i < nn; ++i) { loffs[i] = run; run += ldeg[i]; }
    }
    __syncthreads();
    for (int i = threadIdx.x; i < nn; i += 256) {
        deg[base_node + i]  = ldeg[i];
        offs[base_node + i] = start + loffs[i];
    }
    for (int i = threadIdx.x; i < cnt; i += 256) {
        unsigned p = binned[start + i];
        int ln = p >> 26;
        int pos = start + loffs[ln] + atomicAdd(&lcur[ln], 1);  // LDS atomic
        esrc[pos] = (int)(p & ((1u << 26) - 1));
    }
}

// ========== fallback CSR build (direct, node-level scan) ===================
__global__ __launch_bounds__(256) void k_hist(const int* __restrict__ dst,
                                              int* __restrict__ deg, int n_edges) {
    int e = blockIdx.x * 256 + threadIdx.x;
    if (e < n_edges) atomicAdd(&deg[dst[e]], 1);
}

__global__ __launch_bounds__(256) void k_scatter_idx(
    const int* __restrict__ src, const int* __restrict__ dst,
    const int* __restrict__ offs, int* __restrict__ cursor,
    int* __restrict__ esrc, int n_edges) {
    int e = blockIdx.x * 256 + threadIdx.x;
    if (e >= n_edges) return;
    int d = dst[e];
    int pos = offs[d] + atomicAdd(&cursor[d], 1);
    esrc[pos] = src[e];
}

// ========== gather hW rows + norm + bias + LayerNorm + ReLU ================
__global__ __launch_bounds__(256) void k_gather_ln(
    const unsigned* __restrict__ hb, const int* __restrict__ esrc,
    const int* __restrict__ offs, const int* __restrict__ deg,
    const float* __restrict__ bias, const float* __restrict__ gamma,
    const float* __restrict__ beta, float* __restrict__ out, int n_nodes) {
    int t = blockIdx.x * 256 + threadIdx.x;
    int node = t >> 6;
    int lane = t & 63;
    if (node >= n_nodes) return;
    int start = offs[node];
    int dn = deg[node];
    float ax = 0.0f, ay = 0.0f;
    int i = 0;
    for (; i + 8 <= dn; i += 8) {
        #pragma unroll
        for (int u = 0; u < 8; ++u) {
            int s = esrc[start + i + u];
            unsigned v = hb[(size_t)s * 64 + lane];
            ax += bf_lo(v); ay += bf_hi(v);
        }
    }
    for (; i < dn; ++i) {
        int s = esrc[start + i];
        unsigned v = hb[(size_t)s * 64 + lane];
        ax += bf_lo(v); ay += bf_hi(v);
    }
    float nv = dn > 0 ? 1.0f / (float)dn : 0.0f;
    float fx = ax * nv + bias[2 * lane];
    float fy = ay * nv + bias[2 * lane + 1];

    float s = fx + fy, q = fx * fx + fy * fy;
    #pragma unroll
    for (int m = 1; m < 64; m <<= 1) {
        s += __shfl_xor(s, m);
        q += __shfl_xor(q, m);
    }
    float mu   = s * (1.0f / F);
    float var  = q * (1.0f / F) - mu * mu;
    float rstd = rsqrtf(var + 1e-5f);

    float y0 = fmaxf((fx - mu) * rstd * gamma[2 * lane]     + beta[2 * lane],     0.0f);
    float y1 = fmaxf((fy - mu) * rstd * gamma[2 * lane + 1] + beta[2 * lane + 1], 0.0f);
    ((float2*)out)[(size_t)node * 64 + lane] = make_float2(y0, y1);
}

extern "C" void kernel_launch(void* const* d_in, const int* in_sizes, int n_in,
                              void* d_out, int out_size, void* d_ws, size_t ws_size,
                              hipStream_t stream) {
    const float* h      = (const float*)d_in[0];
    const float* weight = (const float*)d_in[1];
    const float* bias   = (const float*)d_in[2];
    const float* gamma  = (const float*)d_in[3];
    const float* beta   = (const float*)d_in[4];
    const int*   src    = (const int*)d_in[5];
    const int*   dst    = (const int*)d_in[6];

    const int n_nodes = in_sizes[0] / F;
    const int n_edges = in_sizes[5];

    float* x = (float*)d_out;

    const int nb = (n_nodes + (1 << BSHIFT) - 1) >> BSHIFT;
    const int len = nb * NBLK;
    const int nscan = (len + SCANB - 1) / SCANB;
    // guards: scan_b capacity, pack bits (6-bit local dst + 26-bit src)
    const bool shift_ok = (nb <= MAXNB) && (nscan <= 512) && (n_nodes <= (1 << 26));

    // ws ints: deg[N] | offs[N] | esrc[E] | hb[N*64 u32] | bsum[1024] |
    //          mat[nb*NBLK] | binned[E u32]   (fallback: cursor = mat slot)
    int* deg    = (int*)d_ws;
    int* offs   = deg + n_nodes;
    int* esrc   = offs + n_nodes;
    unsigned* hb = (unsigned*)(esrc + n_edges);
    int* bsum   = (int*)(hb + (size_t)n_nodes * 64);
    int* mat    = bsum + 1024;
    unsigned* binned = (unsigned*)(mat + (size_t)len);
    int* cursor = mat;

    size_t need_common = ((size_t)2 * n_nodes + (size_t)n_edges + 1024) * sizeof(int)
                       + (size_t)n_nodes * 64 * sizeof(unsigned);
    size_t need_new  = need_common + ((size_t)len + (size_t)n_edges) * sizeof(int);
    size_t need_fall = need_common + (size_t)n_nodes * sizeof(int);
    bool use_new = shift_ok && ws_size >= need_new;

    const int gb = (n_nodes + 63) / 64;

    if (use_new) {
        // GEMM || hist in one kernel (role split, no grid sync)
        k_gemm_hist<<<NBLK + gb, 256, 0, stream>>>(h, weight, hb, dst, mat,
                                                   n_nodes, n_edges, nb, NBLK);
        k_scan_a<<<nscan, SCANB, 0, stream>>>(mat, mat, bsum, len);
        k_scan_b<<<1, 512, 0, stream>>>(bsum, nscan);
        const int epb = (n_edges + NBLK - 1) / NBLK;
        k_part_scatter<<<NBLK, 256, 0, stream>>>(src, dst, mat, bsum, binned,
                                                 n_edges, nb, epb);
        k_bin_to_csr<<<nb, 256, 0, stream>>>(binned, mat, bsum, deg, offs, esrc,
                                             n_edges, n_nodes, nb);
    } else if (ws_size >= need_fall) {
        k_gemm_hist<<<gb, 256, 0, stream>>>(h, weight, hb, dst, mat,
                                            n_nodes, n_edges, nb, 0);
        const int nscan2 = (n_nodes + SCANB - 1) / SCANB;
        hipMemsetAsync(deg, 0, (size_t)n_nodes * sizeof(int), stream);
        hipMemsetAsync(cursor, 0, (size_t)n_nodes * sizeof(int), stream);
        k_hist<<<(n_edges + 255) / 256, 256, 0, stream>>>(dst, deg, n_edges);
        k_scan_a<<<nscan2, SCANB, 0, stream>>>(deg, offs, bsum, n_nodes);
        k_scan_b<<<1, 512, 0, stream>>>(bsum, nscan2);
        k_scan_c<<<nscan2, SCANB, 0, stream>>>(offs, bsum, n_nodes);
        k_scatter_idx<<<(n_edges + 255) / 256, 256, 0, stream>>>(
            src, dst, offs, cursor, esrc, n_edges);
    }

    int gblocks = (int)(((size_t)n_nodes * 64 + 255) / 256);
    k_gather_ln<<<gblocks, 256, 0, stream>>>(hb, esrc, offs, deg,
                                             bias, gamma, beta, x, n_nodes);
}

// Round 11
// 144.751 us; speedup vs baseline: 6.2022x; 1.0971x over previous
//
#include <hip/hip_runtime.h>

#define F 128
#define SCANB 1024
#define NBLK 128        // hist/scatter width == mat columns
#define BSHIFT 6        // 64 nodes per bucket
#define MAXNB 4096      // nb guard (scan_b / lbase capacity)
#define SMEM_BYTES 43264  // wt(34816) + xs[4][4][132](8448)

typedef __attribute__((ext_vector_type(8))) short short8;
typedef __attribute__((ext_vector_type(4))) float f32x4;

static __device__ __forceinline__ short f2bf(float f) {
    union { float f; unsigned u; } v; v.f = f;
    unsigned r = v.u + 0x7FFF + ((v.u >> 16) & 1);   // round-to-nearest-even
    return (short)(r >> 16);
}
static __device__ __forceinline__ float bf_lo(unsigned u) {
    return __builtin_bit_cast(float, u << 16);
}
static __device__ __forceinline__ float bf_hi(unsigned u) {
    return __builtin_bit_cast(float, u & 0xFFFF0000u);
}
static __device__ __forceinline__ uint4 pack8(float a0,float a1,float a2,float a3,
                                              float a4,float a5,float a6,float a7) {
    uint4 o;
    o.x = ((unsigned)(unsigned short)f2bf(a1) << 16) | (unsigned short)f2bf(a0);
    o.y = ((unsigned)(unsigned short)f2bf(a3) << 16) | (unsigned short)f2bf(a2);
    o.z = ((unsigned)(unsigned short)f2bf(a5) << 16) | (unsigned short)f2bf(a4);
    o.w = ((unsigned)(unsigned short)f2bf(a7) << 16) | (unsigned short)f2bf(a6);
    return o;
}

// ========== role-split kernel: blocks<hblk do dst-hist, rest do hW GEMM ====
__global__ __launch_bounds__(256) void k_gemm_hist(
    const float* __restrict__ h, const float* __restrict__ w,
    unsigned* __restrict__ hb, const int* __restrict__ dst,
    int* __restrict__ mat, int n_nodes, int n_edges, int nb, int hblk) {
    __shared__ alignas(16) char smem[SMEM_BYTES];
    const int tid = threadIdx.x;
    const int bid = blockIdx.x;

    if (bid < hblk) {
        // ---- histogram role ----
        int* lh = (int*)smem;
        for (int i = tid; i < nb; i += 256) lh[i] = 0;
        __syncthreads();
        const int epb = (n_edges + hblk - 1) / hblk;
        const int e0 = bid * epb, e1 = min(e0 + epb, n_edges);
        for (int e = e0 + tid; e < e1; e += 256)
            atomicAdd(&lh[dst[e] >> BSHIFT], 1);
        __syncthreads();
        for (int i = tid; i < nb; i += 256)
            mat[(size_t)i * NBLK + bid] = lh[i];
        return;
    }

    // ---- GEMM role: rows [base, base+64) ----
    short* wt = (short*)smem;               // [128*136] bf16 W^T  (34816 B)
    float* xs = (float*)(smem + 34816);     // [4][4][132] per-wave C bounce
    {
        int n = tid & 127;
        for (int k = tid >> 7; k < 128; k += 2)
            wt[n * 136 + k] = f2bf(w[(size_t)k * 128 + n]);
    }
    __syncthreads();

    const int wv = tid >> 6, l = tid & 63, lr = l & 15, lk = l >> 4, q = l & 15;
    const int base = (bid - hblk) * 64;
    if (base >= n_nodes) return;
    const int row = base + wv * 16 + lr;
    const bool valid = row < n_nodes;

    short8 af[4];
    #pragma unroll
    for (int kk = 0; kk < 4; ++kk) {
        int k0 = kk * 32 + lk * 8;
        float4 a0{0,0,0,0}, a1{0,0,0,0};
        if (valid) {
            a0 = *(const float4*)(h + (size_t)row * F + k0);
            a1 = *(const float4*)(h + (size_t)row * F + k0 + 4);
        }
        af[kk] = short8{ f2bf(a0.x), f2bf(a0.y), f2bf(a0.z), f2bf(a0.w),
                         f2bf(a1.x), f2bf(a1.y), f2bf(a1.z), f2bf(a1.w) };
    }
    f32x4 acc[8];
    #pragma unroll
    for (int n = 0; n < 8; ++n) acc[n] = f32x4{0, 0, 0, 0};
    #pragma unroll
    for (int kk = 0; kk < 4; ++kk) {
        const int kb = kk * 32 + lk * 8;
        #pragma unroll
        for (int n = 0; n < 8; ++n) {
            short8 bfr = *(const short8*)(&wt[(n * 16 + lr) * 136 + kb]);
            acc[n] = __builtin_amdgcn_mfma_f32_16x16x32_bf16(af[kk], bfr, acc[n], 0, 0, 0);
        }
    }
    // per-r bounce: row lk*4+r lives in LDS slot lk
    float* xw = xs + wv * (4 * 132);
    #pragma unroll
    for (int r = 0; r < 4; ++r) {
        #pragma unroll
        for (int n = 0; n < 8; ++n)
            xw[lk * 132 + n * 16 + lr] = acc[n][r];
        int grow = base + wv * 16 + lk * 4 + r;
        float4 a = *(const float4*)&xw[lk * 132 + q * 8];
        float4 b = *(const float4*)&xw[lk * 132 + q * 8 + 4];
        uint4 o = pack8(a.x, a.y, a.z, a.w, b.x, b.y, b.z, b.w);
        if (grow < n_nodes)
            ((uint4*)hb)[(size_t)grow * 16 + q] = o;
    }
}

// ========== exclusive scan (chunked; bsum holds per-chunk totals) ==========
__global__ __launch_bounds__(SCANB) void k_scan_a(const int* in, int* out,
                                                  int* bsum, int n) {
    __shared__ int tmp[SCANB];
    int i = blockIdx.x * SCANB + threadIdx.x;
    int v = (i < n) ? in[i] : 0;
    tmp[threadIdx.x] = v;
    __syncthreads();
    for (int off = 1; off < SCANB; off <<= 1) {
        int t = (threadIdx.x >= off) ? tmp[threadIdx.x - off] : 0;
        __syncthreads();
        tmp[threadIdx.x] += t;
        __syncthreads();
    }
    if (i < n) out[i] = tmp[threadIdx.x] - v;
    if (threadIdx.x == SCANB - 1) bsum[blockIdx.x] = tmp[SCANB - 1];
}

__global__ __launch_bounds__(512) void k_scan_b(int* bsum, int nb) {
    __shared__ int tmp[512];
    int i = threadIdx.x;
    int v = (i < nb) ? bsum[i] : 0;
    tmp[i] = v;
    __syncthreads();
    for (int off = 1; off < 512; off <<= 1) {
        int t = (i >= off) ? tmp[i - off] : 0;
        __syncthreads();
        tmp[i] += t;
        __syncthreads();
    }
    if (i < nb) bsum[i] = tmp[i] - v;
}

__global__ __launch_bounds__(SCANB) void k_scan_c(int* out, const int* bsum, int n) {
    int i = blockIdx.x * SCANB + threadIdx.x;
    if (i < n) out[i] += bsum[blockIdx.x];
}

// ========== binned scatter; scan_c folded in via bsum lookup ===============
__global__ __launch_bounds__(256) void k_part_scatter(
    const int* __restrict__ src, const int* __restrict__ dst,
    const int* __restrict__ mat, const int* __restrict__ bsum,
    unsigned* __restrict__ binned, int n_edges, int nb, int epb) {
    __shared__ int lbase[MAXNB];
    const int bid = blockIdx.x;
    for (int i = threadIdx.x; i < nb; i += 256) {
        int idx = i * NBLK + bid;
        lbase[i] = mat[idx] + bsum[idx >> 10];
    }
    __syncthreads();
    int e0 = bid * epb;
    int e1 = min(e0 + epb, n_edges);
    for (int e = e0 + threadIdx.x; e < e1; e += 256) {
        int d = dst[e];
        int b = d >> BSHIFT;
        int pos = atomicAdd(&lbase[b], 1);   // LDS atomic only
        binned[pos] = ((unsigned)(d & ((1 << BSHIFT) - 1)) << 26) | (unsigned)src[e];
    }
}

// ========== per-bucket CSR finalize; scan_c folded in ======================
__global__ __launch_bounds__(256) void k_bin_to_csr(
    const unsigned* __restrict__ binned, const int* __restrict__ mat,
    const int* __restrict__ bsum, int* __restrict__ deg, int* __restrict__ offs,
    int* __restrict__ esrc, int n_edges, int n_nodes, int nb) {
    __shared__ int ldeg[64], loffs[64], lcur[64];
    int b = blockIdx.x;
    int i0 = b * NBLK;
    int start = mat[i0] + bsum[i0 >> 10];
    int end = n_edges;
    if (b + 1 < nb) {
        int i1 = (b + 1) * NBLK;
        end = mat[i1] + bsum[i1 >> 10];
    }
    int cnt = end - start;
    int base_node = b << BSHIFT;
    int nn = min(1 << BSHIFT, n_nodes - base_node);
    for (int i = threadIdx.x; i < nn; i += 256) { ldeg[i] = 0; lcur[i] = 0; }
    __syncthreads();
    for (int i = threadIdx.x; i < cnt; i += 256)
        atomicAdd(&ldeg[binned[start + i] >> 26], 1);
    __syncthreads();
    if (threadIdx.x == 0) {
        int run = 0;
        for (int i = 0; i < nn; ++i) { loffs[i] = run; run += ldeg[i]; }
    }
    __syncthreads();
    for (int i = threadIdx.x; i < nn; i += 256) {
        deg[base_node + i]  = ldeg[i];
        offs[base_node + i] = start + loffs[i];
    }
    for (int i = threadIdx.x; i < cnt; i += 256) {
        unsigned p = binned[start + i];
        int ln = p >> 26;
        int pos = start + loffs[ln] + atomicAdd(&lcur[ln], 1);  // LDS atomic
        esrc[pos] = (int)(p & ((1u << 26) - 1));
    }
}

// ========== fallback CSR build (direct, node-level scan) ===================
__global__ __launch_bounds__(256) void k_hist(const int* __restrict__ dst,
                                              int* __restrict__ deg, int n_edges) {
    int e = blockIdx.x * 256 + threadIdx.x;
    if (e < n_edges) atomicAdd(&deg[dst[e]], 1);
}

__global__ __launch_bounds__(256) void k_scatter_idx(
    const int* __restrict__ src, const int* __restrict__ dst,
    const int* __restrict__ offs, int* __restrict__ cursor,
    int* __restrict__ esrc, int n_edges) {
    int e = blockIdx.x * 256 + threadIdx.x;
    if (e >= n_edges) return;
    int d = dst[e];
    int pos = offs[d] + atomicAdd(&cursor[d], 1);
    esrc[pos] = src[e];
}

// ========== gather hW rows + norm + bias + LayerNorm + ReLU (wide) =========
// One wave per node. Lane l = (g = l>>4 : edge subgroup, q = l&15 : 16B chunk).
// Each iteration covers 4 edges with one dwordx4 per lane (8 features).
__global__ __launch_bounds__(256) void k_gather_ln(
    const unsigned* __restrict__ hb, const int* __restrict__ esrc,
    const int* __restrict__ offs, const int* __restrict__ deg,
    const float* __restrict__ bias, const float* __restrict__ gamma,
    const float* __restrict__ beta, float* __restrict__ out, int n_nodes) {
    int t = blockIdx.x * 256 + threadIdx.x;
    int node = t >> 6;
    int l = t & 63;
    if (node >= n_nodes) return;
    const int g = l >> 4;
    const int q = l & 15;

    // per-lane params for features q*8 .. q*8+7
    float4 bs0 = *(const float4*)(bias  + q * 8);
    float4 bs1 = *(const float4*)(bias  + q * 8 + 4);
    float4 gm0 = *(const float4*)(gamma + q * 8);
    float4 gm1 = *(const float4*)(gamma + q * 8 + 4);
    float4 bt0 = *(const float4*)(beta  + q * 8);
    float4 bt1 = *(const float4*)(beta  + q * 8 + 4);

    const int start = offs[node];
    const int dn = deg[node];
    const int end = start + dn;

    float a0=0,a1=0,a2=0,a3=0,a4=0,a5=0,a6=0,a7=0;
    int i = start;
    // main loop: 8 edges per iteration (2 independent dwordx4 loads per lane)
    for (; i + 8 <= end; i += 8) {
        int s0 = esrc[i + g];
        int s1 = esrc[i + 4 + g];
        uint4 v0 = *((const uint4*)(hb + (size_t)s0 * 64 + q * 4));
        uint4 v1 = *((const uint4*)(hb + (size_t)s1 * 64 + q * 4));
        a0 += bf_lo(v0.x) + bf_lo(v1.x); a1 += bf_hi(v0.x) + bf_hi(v1.x);
        a2 += bf_lo(v0.y) + bf_lo(v1.y); a3 += bf_hi(v0.y) + bf_hi(v1.y);
        a4 += bf_lo(v0.z) + bf_lo(v1.z); a5 += bf_hi(v0.z) + bf_hi(v1.z);
        a6 += bf_lo(v0.w) + bf_lo(v1.w); a7 += bf_hi(v0.w) + bf_hi(v1.w);
    }
    // tail: up to 2 masked 4-edge iterations
    for (; i < end; i += 4) {
        int e = i + g;
        if (e < end) {
            int s = esrc[e];
            uint4 v = *((const uint4*)(hb + (size_t)s * 64 + q * 4));
            a0 += bf_lo(v.x); a1 += bf_hi(v.x);
            a2 += bf_lo(v.y); a3 += bf_hi(v.y);
            a4 += bf_lo(v.z); a5 += bf_hi(v.z);
            a6 += bf_lo(v.w); a7 += bf_hi(v.w);
        }
    }
    // combine the 4 edge-subgroups (lanes g=0..3 share q)
    #pragma unroll
    for (int m = 16; m <= 32; m <<= 1) {
        a0 += __shfl_xor(a0, m); a1 += __shfl_xor(a1, m);
        a2 += __shfl_xor(a2, m); a3 += __shfl_xor(a3, m);
        a4 += __shfl_xor(a4, m); a5 += __shfl_xor(a5, m);
        a6 += __shfl_xor(a6, m); a7 += __shfl_xor(a7, m);
    }
    const float nv = dn > 0 ? 1.0f / (float)dn : 0.0f;
    float f0 = a0 * nv + bs0.x, f1 = a1 * nv + bs0.y;
    float f2 = a2 * nv + bs0.z, f3 = a3 * nv + bs0.w;
    float f4 = a4 * nv + bs1.x, f5 = a5 * nv + bs1.y;
    float f6 = a6 * nv + bs1.z, f7 = a7 * nv + bs1.w;

    // LN stats across the 16 q-chunks (masks 1..8 vary q only)
    float s  = ((f0 + f1) + (f2 + f3)) + ((f4 + f5) + (f6 + f7));
    float q2 = ((f0*f0 + f1*f1) + (f2*f2 + f3*f3)) + ((f4*f4 + f5*f5) + (f6*f6 + f7*f7));
    #pragma unroll
    for (int m = 1; m <= 8; m <<= 1) {
        s  += __shfl_xor(s, m);
        q2 += __shfl_xor(q2, m);
    }
    float mu   = s * (1.0f / F);
    float var  = q2 * (1.0f / F) - mu * mu;
    float rstd = rsqrtf(var + 1e-5f);

    if (g == 0) {
        float4 o0, o1;
        o0.x = fmaxf((f0 - mu) * rstd * gm0.x + bt0.x, 0.0f);
        o0.y = fmaxf((f1 - mu) * rstd * gm0.y + bt0.y, 0.0f);
        o0.z = fmaxf((f2 - mu) * rstd * gm0.z + bt0.z, 0.0f);
        o0.w = fmaxf((f3 - mu) * rstd * gm0.w + bt0.w, 0.0f);
        o1.x = fmaxf((f4 - mu) * rstd * gm1.x + bt1.x, 0.0f);
        o1.y = fmaxf((f5 - mu) * rstd * gm1.y + bt1.y, 0.0f);
        o1.z = fmaxf((f6 - mu) * rstd * gm1.z + bt1.z, 0.0f);
        o1.w = fmaxf((f7 - mu) * rstd * gm1.w + bt1.w, 0.0f);
        float* op = out + (size_t)node * F + q * 8;
        *(float4*)op = o0;
        *(float4*)(op + 4) = o1;
    }
}

extern "C" void kernel_launch(void* const* d_in, const int* in_sizes, int n_in,
                              void* d_out, int out_size, void* d_ws, size_t ws_size,
                              hipStream_t stream) {
    const float* h      = (const float*)d_in[0];
    const float* weight = (const float*)d_in[1];
    const float* bias   = (const float*)d_in[2];
    const float* gamma  = (const float*)d_in[3];
    const float* beta   = (const float*)d_in[4];
    const int*   src    = (const int*)d_in[5];
    const int*   dst    = (const int*)d_in[6];

    const int n_nodes = in_sizes[0] / F;
    const int n_edges = in_sizes[5];

    float* x = (float*)d_out;

    const int nb = (n_nodes + (1 << BSHIFT) - 1) >> BSHIFT;
    const int len = nb * NBLK;
    const int nscan = (len + SCANB - 1) / SCANB;
    const bool shift_ok = (nb <= MAXNB) && (nscan <= 512) && (n_nodes <= (1 << 26));

    // ws ints: deg[N] | offs[N] | esrc[E] | hb[N*64 u32] | bsum[1024] |
    //          mat[nb*NBLK] | binned[E u32]   (fallback: cursor = mat slot)
    int* deg    = (int*)d_ws;
    int* offs   = deg + n_nodes;
    int* esrc   = offs + n_nodes;
    unsigned* hb = (unsigned*)(esrc + n_edges);
    int* bsum   = (int*)(hb + (size_t)n_nodes * 64);
    int* mat    = bsum + 1024;
    unsigned* binned = (unsigned*)(mat + (size_t)len);
    int* cursor = mat;

    size_t need_common = ((size_t)2 * n_nodes + (size_t)n_edges + 1024) * sizeof(int)
                       + (size_t)n_nodes * 64 * sizeof(unsigned);
    size_t need_new  = need_common + ((size_t)len + (size_t)n_edges) * sizeof(int);
    size_t need_fall = need_common + (size_t)n_nodes * sizeof(int);
    bool use_new = shift_ok && ws_size >= need_new;

    const int gb = (n_nodes + 63) / 64;

    if (use_new) {
        k_gemm_hist<<<NBLK + gb, 256, 0, stream>>>(h, weight, hb, dst, mat,
                                                   n_nodes, n_edges, nb, NBLK);
        k_scan_a<<<nscan, SCANB, 0, stream>>>(mat, mat, bsum, len);
        k_scan_b<<<1, 512, 0, stream>>>(bsum, nscan);
        const int epb = (n_edges + NBLK - 1) / NBLK;
        k_part_scatter<<<NBLK, 256, 0, stream>>>(src, dst, mat, bsum, binned,
                                                 n_edges, nb, epb);
        k_bin_to_csr<<<nb, 256, 0, stream>>>(binned, mat, bsum, deg, offs, esrc,
                                             n_edges, n_nodes, nb);
    } else if (ws_size >= need_fall) {
        k_gemm_hist<<<gb, 256, 0, stream>>>(h, weight, hb, dst, mat,
                                            n_nodes, n_edges, nb, 0);
        const int nscan2 = (n_nodes + SCANB - 1) / SCANB;
        hipMemsetAsync(deg, 0, (size_t)n_nodes * sizeof(int), stream);
        hipMemsetAsync(cursor, 0, (size_t)n_nodes * sizeof(int), stream);
        k_hist<<<(n_edges + 255) / 256, 256, 0, stream>>>(dst, deg, n_edges);
        k_scan_a<<<nscan2, SCANB, 0, stream>>>(deg, offs, bsum, n_nodes);
        k_scan_b<<<1, 512, 0, stream>>>(bsum, nscan2);
        k_scan_c<<<nscan2, SCANB, 0, stream>>>(offs, bsum, n_nodes);
        k_scatter_idx<<<(n_edges + 255) / 256, 256, 0, stream>>>(
            src, dst, offs, cursor, esrc, n_edges);
    }

    int gblocks = (int)(((size_t)n_nodes * 64 + 255) / 256);
    k_gather_ln<<<gblocks, 256, 0, stream>>>(hb, esrc, offs, deg,
                                             bias, gamma, beta, x, n_nodes);
}